// Round 1
// 1687.057 us; speedup vs baseline: 1.7256x; 1.7256x over previous
//
#include <hip/hip_runtime.h>
#include <hip/hip_bf16.h>

typedef __bf16 bf16x8 __attribute__((ext_vector_type(8)));
typedef float  f32x4  __attribute__((ext_vector_type(4)));

__device__ __forceinline__ void store_bf8(__bf16* dst, float4 a, float4 b) {
  bf16x8 v;
  v[0] = (__bf16)a.x; v[1] = (__bf16)a.y; v[2] = (__bf16)a.z; v[3] = (__bf16)a.w;
  v[4] = (__bf16)b.x; v[5] = (__bf16)b.y; v[6] = (__bf16)b.z; v[7] = (__bf16)b.w;
  *(bf16x8*)dst = v;
}

// Coherent (agent-scope, sc0 sc1) 16B load of a bf16x8 fragment: bypasses the
// non-coherent L1/per-XCD-L2, reads straight from the coherent point.
__device__ __forceinline__ bf16x8 load_coh16(const __bf16* p) {
  union { unsigned long long u[2]; bf16x8 v; } r;
  r.u[0] = __hip_atomic_load((const unsigned long long*)p,     __ATOMIC_RELAXED, __HIP_MEMORY_SCOPE_AGENT);
  r.u[1] = __hip_atomic_load((const unsigned long long*)p + 1, __ATOMIC_RELAXED, __HIP_MEMORY_SCOPE_AGENT);
  return r.v;
}

// Coherent 2B bf16 store (write-through to the coherent point).
__device__ __forceinline__ void store_coh_bf16(__bf16* p, float v) {
  __bf16 b = (__bf16)v;
  unsigned short u;
  __builtin_memcpy(&u, &b, 2);
  __hip_atomic_store((unsigned short*)p, u, __ATOMIC_RELAXED, __HIP_MEMORY_SCOPE_AGENT);
}

// f32 -> bf16 bulk convert, 8 elems/thread
__global__ __launch_bounds__(256) void cvt_f32_bf16(
    const float* __restrict__ s, __bf16* __restrict__ d, long n8)
{
  long i = (long)blockIdx.x * 256 + threadIdx.x;
  if (i >= n8) return;
  const float4* sp = (const float4*)s + i * 2;
  store_bf8(d + i * 8, sp[0], sp[1]);
}

// dst[r,:] = bf16(emb[idx[r],:]), rows of 512; one 64-thread block per row
__global__ __launch_bounds__(64) void gather_cvt(
    const float* __restrict__ emb, const int* __restrict__ idx, __bf16* __restrict__ dst)
{
  const int r = blockIdx.x;
  const long row = idx[r];
  const float4* sp = (const float4*)(emb + row * 512) + threadIdx.x * 2;
  store_bf8(dst + (long)r * 512 + threadIdx.x * 8, sp[0], sp[1]);
}

// ---------------------------------------------------------------------------
// GEMM: C[M,N] (fp32) = A[M,512](bf16) @ B[N,512](bf16)^T + bias[N](fp32)
// Block = 256 threads (4 waves), block tile 64(M) x 64(N), K=512.
// ---------------------------------------------------------------------------
__global__ __launch_bounds__(256) void gemm_bt(
    const __bf16* __restrict__ A, const __bf16* __restrict__ B,
    const float* __restrict__ bias, float* __restrict__ C, int M, int N)
{
  const int wave = threadIdx.x >> 6;
  const int lane = threadIdx.x & 63;
  const int l16 = lane & 15;
  const int quad = lane >> 4;

  const int mt = blockIdx.x * 4 + wave;
  const bool active = (mt * 16) < M;
  int row = mt * 16 + l16;
  if (row >= M) row = M - 1;

  const int n0 = blockIdx.y * 64;
  const __bf16* __restrict__ Ab = A + (long)row * 512 + quad * 8;

  const __bf16* bp[4];
#pragma unroll
  for (int i = 0; i < 4; ++i)
    bp[i] = B + (long)(n0 + i * 16 + l16) * 512 + quad * 8;

  f32x4 acc[4];
#pragma unroll
  for (int i = 0; i < 4; ++i) acc[i] = (f32x4){0.f, 0.f, 0.f, 0.f};

#pragma unroll
  for (int ks = 0; ks < 16; ++ks) {
    bf16x8 a = *(const bf16x8*)(Ab + ks * 32);
#pragma unroll
    for (int i = 0; i < 4; ++i) {
      bf16x8 b = *(const bf16x8*)(bp[i] + ks * 32);
      acc[i] = __builtin_amdgcn_mfma_f32_16x16x32_bf16(a, b, acc[i], 0, 0, 0);
    }
  }

  if (!active) return;
  const int crow = mt * 16 + quad * 4;
#pragma unroll
  for (int i = 0; i < 4; ++i) {
    const int n = n0 + i * 16 + l16;
    const float bv = bias ? bias[n] : 0.0f;
#pragma unroll
    for (int r = 0; r < 4; ++r)
      C[(long)(crow + r) * N + n] = acc[i][r] + bv;
  }
}

// ---------------------------------------------------------------------------
// Pipelined 2-layer GRU recurrence. Grid = 64 WGs x 128 threads.
//   WGs  0..31 : layer 0 (GI precomputed in f32, (T,32,1536))
//   WGs 32..63 : layer 1 (computes gi = y0[t] @ Wih1^T on the fly via MFMA)
// WG c owns hidden cols [c*16, c*16+16). Per layer, h is exchanged through
// WRITE-ONCE timestep slots Y[t+1] (T+1 slots of 32x512 bf16) using relaxed
// agent-scope atomic stores/loads (sc0 sc1 -> coherent point); no threadfence,
// no cache invalidates. f32 master h lives in registers (4 elems/thread,
// matching the MFMA C-fragment), persisted to hf only at stage boundaries.
// Layer 1 at step t waits ctr0 >= 32(t+1) (y0[t] ready) and ctr1 >= 32t.
// ---------------------------------------------------------------------------
__global__ __launch_bounds__(128) void gru2_pipe(
    const float* __restrict__ GI,
    const float* __restrict__ Whh0, const float* __restrict__ bhh0,
    const float* __restrict__ Wih1, const float* __restrict__ bih1,
    const float* __restrict__ Whh1, const float* __restrict__ bhh1,
    __bf16* __restrict__ Y0, __bf16* __restrict__ Y1,   // (T+1,32,512) slots
    const __bf16* __restrict__ h0i, const __bf16* __restrict__ h1i,
    float* __restrict__ hf0, float* __restrict__ hf1,   // 32x512 f32 masters
    unsigned* __restrict__ ctr0, unsigned* __restrict__ ctr1, int T)
{
  __shared__ __align__(16) __bf16 wh[48 * 520];  // Whh slice (own layer)
  __shared__ __align__(16) __bf16 wi[48 * 520];  // Wih1 slice (layer 1 only)

  const int tid = threadIdx.x;
  const int L   = blockIdx.x >> 5;
  const int c   = blockIdx.x & 31;
  const int w   = tid >> 6;
  const int lane = tid & 63;
  const int l16 = lane & 15;
  const int quad = lane >> 4;

  const float* __restrict__ Whh = L ? Whh1 : Whh0;
  const float* __restrict__ bhh = L ? bhh1 : bhh0;
  __bf16* __restrict__ Yown = L ? Y1 : Y0;
  const __bf16* __restrict__ hini = L ? h1i : h0i;
  float* __restrict__ hf = L ? hf1 : hf0;
  unsigned* __restrict__ cOwn = L ? ctr1 : ctr0;

  // Preload+convert Whh slice (and Wih1 slice for layer 1) into LDS.
  for (int ch = tid; ch < 48 * 64; ch += 128) {
    const int lr = ch >> 6, kc = ch & 63;
    const int g = lr >> 4, j = lr & 15;
    const float4* sp = (const float4*)(Whh + (long)(g * 512 + c * 16 + j) * 512) + kc * 2;
    store_bf8(&wh[lr * 520 + kc * 8], sp[0], sp[1]);
  }
  if (L) {
    for (int ch = tid; ch < 48 * 64; ch += 128) {
      const int lr = ch >> 6, kc = ch & 63;
      const int g = lr >> 4, j = lr & 15;
      const float4* sp = (const float4*)(Wih1 + (long)(g * 512 + c * 16 + j) * 512) + kc * 2;
      store_bf8(&wi[lr * 520 + kc * 8], sp[0], sp[1]);
    }
  }

  // Biases per output col (fused: r/z get bih+bhh on layer 1).
  float bR = bhh[0 * 512 + c * 16 + l16];
  float bZ = bhh[1 * 512 + c * 16 + l16];
  float bH = bhh[2 * 512 + c * 16 + l16];
  float bN = 0.f;
  if (L) {
    bR += bih1[0 * 512 + c * 16 + l16];
    bZ += bih1[1 * 512 + c * 16 + l16];
    bN  = bih1[2 * 512 + c * 16 + l16];
  }
  __syncthreads();

  // This thread's 4 output elements (MFMA C layout): rows b0..b0+3, col.
  const int b0  = w * 16 + quad * 4;
  const int col = c * 16 + l16;

  float hprev[4];
#pragma unroll
  for (int r = 0; r < 4; ++r) hprev[r] = hf[(b0 + r) * 512 + col];

  for (int t = 0; t < T; ++t) {
    // Early private loads (no cross-WG dependency): layer-0 gate inputs.
    float giR[4] = {0, 0, 0, 0}, giZ[4] = {0, 0, 0, 0}, giN[4] = {0, 0, 0, 0};
    if (!L) {
      const float* GIt = GI + (long)t * 49152;
#pragma unroll
      for (int r = 0; r < 4; ++r) {
        const float* gp = GIt + (b0 + r) * 1536 + col;
        giR[r] = gp[0];
        giZ[r] = gp[512];
        giN[r] = gp[1024];
      }
    }

    // Wait for producers (leader spins on coherent counter reads).
    if (tid == 0) {
      if (L) {
        const unsigned tgt0 = 32u * (unsigned)(t + 1);
        while (__hip_atomic_load(ctr0, __ATOMIC_RELAXED, __HIP_MEMORY_SCOPE_AGENT) < tgt0)
          __builtin_amdgcn_s_sleep(1);
        if (t) {
          const unsigned tgt1 = 32u * (unsigned)t;
          while (__hip_atomic_load(ctr1, __ATOMIC_RELAXED, __HIP_MEMORY_SCOPE_AGENT) < tgt1)
            __builtin_amdgcn_s_sleep(1);
        }
      } else if (t) {
        const unsigned tgt = 32u * (unsigned)t;
        while (__hip_atomic_load(ctr0, __ATOMIC_RELAXED, __HIP_MEMORY_SCOPE_AGENT) < tgt)
          __builtin_amdgcn_s_sleep(1);
      }
    }
    __syncthreads();

    // Issue ALL coherent fragment loads first (64 in flight max), then MFMA.
    const __bf16* hsrc = t ? (Yown + (long)t * 16384) : hini;
    const __bf16* hA = hsrc + (w * 16 + l16) * 512 + quad * 8;
    bf16x8 ha[16], xa[16];
#pragma unroll
    for (int ks = 0; ks < 16; ++ks) ha[ks] = load_coh16(hA + ks * 32);
    if (L) {
      const __bf16* xA = Y0 + (long)(t + 1) * 16384 + (w * 16 + l16) * 512 + quad * 8;
#pragma unroll
      for (int ks = 0; ks < 16; ++ks) xa[ks] = load_coh16(xA + ks * 32);
    }

    f32x4 accR = {bR, bR, bR, bR};
    f32x4 accZ = {bZ, bZ, bZ, bZ};
    f32x4 accH = {bH, bH, bH, bH};
    f32x4 accN = {bN, bN, bN, bN};

#pragma unroll
    for (int ks = 0; ks < 16; ++ks) {
      const int o = ks * 32 + quad * 8;
      accR = __builtin_amdgcn_mfma_f32_16x16x32_bf16(ha[ks], *(const bf16x8*)&wh[(     l16) * 520 + o], accR, 0, 0, 0);
      accZ = __builtin_amdgcn_mfma_f32_16x16x32_bf16(ha[ks], *(const bf16x8*)&wh[(16 + l16) * 520 + o], accZ, 0, 0, 0);
      accH = __builtin_amdgcn_mfma_f32_16x16x32_bf16(ha[ks], *(const bf16x8*)&wh[(32 + l16) * 520 + o], accH, 0, 0, 0);
    }
    if (L) {
#pragma unroll
      for (int ks = 0; ks < 16; ++ks) {
        const int o = ks * 32 + quad * 8;
        accR = __builtin_amdgcn_mfma_f32_16x16x32_bf16(xa[ks], *(const bf16x8*)&wi[(     l16) * 520 + o], accR, 0, 0, 0);
        accZ = __builtin_amdgcn_mfma_f32_16x16x32_bf16(xa[ks], *(const bf16x8*)&wi[(16 + l16) * 520 + o], accZ, 0, 0, 0);
        accN = __builtin_amdgcn_mfma_f32_16x16x32_bf16(xa[ks], *(const bf16x8*)&wi[(32 + l16) * 520 + o], accN, 0, 0, 0);
      }
    }

    // Gates entirely in registers (C-fragment layout), coherent bf16 stores.
    __bf16* yout = Yown + (long)(t + 1) * 16384;
#pragma unroll
    for (int r = 0; r < 4; ++r) {
      float rs = accR[r], zs = accZ[r], hn = accH[r], nn = accN[r];
      if (!L) { rs += giR[r]; zs += giZ[r]; nn = giN[r]; }
      const float rg = 1.0f / (1.0f + expf(-rs));
      const float zg = 1.0f / (1.0f + expf(-zs));
      const float cand = tanhf(nn + rg * hn);
      const float hnew = (1.0f - zg) * cand + zg * hprev[r];
      hprev[r] = hnew;
      store_coh_bf16(yout + (b0 + r) * 512 + col, hnew);
    }

    // All stores acked at the coherent point, then one release-RMW per WG.
    asm volatile("s_waitcnt vmcnt(0)" ::: "memory");
    __syncthreads();
    if (tid == 0)
      __hip_atomic_fetch_add(cOwn, 1u, __ATOMIC_RELEASE, __HIP_MEMORY_SCOPE_AGENT);
  }

  // Persist f32 master for the next stage (enc -> dec handoff).
#pragma unroll
  for (int r = 0; r < 4; ++r) hf[(b0 + r) * 512 + col] = hprev[r];
}

// ---------------------------------------------------------------------------
// Workspace layout (bytes), total ~59.7 MB:
//  GI    @ 0          12,582,912  (2048*1536 f32; reused enc0/dec0)
//  Xenc  @ 12,582,912  2,097,152
//  Xdec  @ 14,680,064  1,540,096
//  Y0e   @ 16,220,160  2,129,920  (65 slots: slot0 unused, 1..64 = y0 enc)
//  Y1e   @ 18,350,080  2,129,920  (slot 64 = enc layer1 final h)
//  Y0d   @ 20,480,000  1,572,864  (48 slots)
//  Y1d   @ 22,052,864  1,572,864  (slots 1..47 = D1 -> out GEMM A)
//  Wb0   @ 23,625,728  1,572,864  (enc_Wih0 bf16)
//  Wb2   @ 25,198,592  1,572,864  (dec_Wih0 bf16)
//  outWb @ 26,771,456 32,768,000
//  hf0   @ 59,539,456     65,536 ; hf1 @ 59,604,992 65,536
//  zb    @ 59,670,528     32,768  (bf16 zeros = initial h)
//  ctrs  @ 59,703,296      1,024  (4 counters, 128B apart)
// ---------------------------------------------------------------------------
extern "C" void kernel_launch(void* const* d_in, const int* in_sizes, int n_in,
                              void* d_out, int out_size, void* d_ws, size_t ws_size,
                              hipStream_t stream)
{
  const int* src = (const int*)d_in[0];
  const int* trg = (const int*)d_in[1];
  const float* enc_emb  = (const float*)d_in[2];
  const float* enc_Wih0 = (const float*)d_in[3];
  const float* enc_Whh0 = (const float*)d_in[4];
  const float* enc_bih0 = (const float*)d_in[5];
  const float* enc_bhh0 = (const float*)d_in[6];
  const float* enc_Wih1 = (const float*)d_in[7];
  const float* enc_Whh1 = (const float*)d_in[8];
  const float* enc_bih1 = (const float*)d_in[9];
  const float* enc_bhh1 = (const float*)d_in[10];
  const float* dec_emb  = (const float*)d_in[11];
  const float* dec_Wih0 = (const float*)d_in[12];
  const float* dec_Whh0 = (const float*)d_in[13];
  const float* dec_bih0 = (const float*)d_in[14];
  const float* dec_bhh0 = (const float*)d_in[15];
  const float* dec_Wih1 = (const float*)d_in[16];
  const float* dec_Whh1 = (const float*)d_in[17];
  const float* dec_bih1 = (const float*)d_in[18];
  const float* dec_bhh1 = (const float*)d_in[19];
  const float* out_W    = (const float*)d_in[20];
  const float* out_b    = (const float*)d_in[21];

  char* ws = (char*)d_ws;
  float*  GI    = (float*)(ws + 0);
  __bf16* Xenc  = (__bf16*)(ws + 12582912);
  __bf16* Xdec  = (__bf16*)(ws + 14680064);
  __bf16* Y0e   = (__bf16*)(ws + 16220160);
  __bf16* Y1e   = (__bf16*)(ws + 18350080);
  __bf16* Y0d   = (__bf16*)(ws + 20480000);
  __bf16* Y1d   = (__bf16*)(ws + 22052864);
  __bf16* Wb0   = (__bf16*)(ws + 23625728);
  __bf16* Wb2   = (__bf16*)(ws + 25198592);
  __bf16* outWb = (__bf16*)(ws + 26771456);
  float*  hf0   = (float*)(ws + 59539456);
  float*  hf1   = (float*)(ws + 59604992);
  __bf16* zb    = (__bf16*)(ws + 59670528);
  unsigned* ctrs = (unsigned*)(ws + 59703296);

  hipMemsetAsync(hf0, 0, 131072, stream);   // hf0 + hf1
  hipMemsetAsync(zb, 0, 32768, stream);
  hipMemsetAsync(ctrs, 0, 1024, stream);

  gather_cvt<<<2048, 64, 0, stream>>>(enc_emb, src, Xenc);
  gather_cvt<<<1504, 64, 0, stream>>>(dec_emb, trg, Xdec);   // rows 0..1503 = trg[:-1]
  cvt_f32_bf16<<<384, 256, 0, stream>>>(enc_Wih0, Wb0, 98304);
  cvt_f32_bf16<<<384, 256, 0, stream>>>(dec_Wih0, Wb2, 98304);
  cvt_f32_bf16<<<8000, 256, 0, stream>>>(out_W, outWb, 2048000);

  // encoder: GI for layer0, then both layers pipelined in one kernel
  gemm_bt<<<dim3(32, 24), 256, 0, stream>>>(Xenc, Wb0, enc_bih0, GI, 2048, 1536);
  gru2_pipe<<<64, 128, 0, stream>>>(GI, enc_Whh0, enc_bhh0,
                                    enc_Wih1, enc_bih1, enc_Whh1, enc_bhh1,
                                    Y0e, Y1e, zb, zb, hf0, hf1,
                                    ctrs + 0, ctrs + 32, 64);
  // decoder: initial h = encoder finals (Y*e slot 64 bf16, hf* f32 in place)
  gemm_bt<<<dim3(24, 24), 256, 0, stream>>>(Xdec, Wb2, dec_bih0, GI, 1504, 1536);
  gru2_pipe<<<64, 128, 0, stream>>>(GI, dec_Whh0, dec_bhh0,
                                    dec_Wih1, dec_bih1, dec_Whh1, dec_bhh1,
                                    Y0d, Y1d, Y0e + 64 * 16384, Y1e + 64 * 16384, hf0, hf1,
                                    ctrs + 64, ctrs + 96, 47);

  // logits = D1 @ out_W^T + out_b  (D1 = Y1d slots 1..47, contiguous 1504x512)
  gemm_bt<<<dim3(24, 500), 256, 0, stream>>>(Y1d + 16384, outWb, out_b,
                                             (float*)d_out, 1504, 32000);
}

// Round 2
// 1430.660 us; speedup vs baseline: 2.0348x; 1.1792x over previous
//
#include <hip/hip_runtime.h>
#include <hip/hip_bf16.h>

typedef __bf16 bf16x8 __attribute__((ext_vector_type(8)));
typedef float  f32x4  __attribute__((ext_vector_type(4)));

__device__ __forceinline__ void store_bf8(__bf16* dst, float4 a, float4 b) {
  bf16x8 v;
  v[0] = (__bf16)a.x; v[1] = (__bf16)a.y; v[2] = (__bf16)a.z; v[3] = (__bf16)a.w;
  v[4] = (__bf16)b.x; v[5] = (__bf16)b.y; v[6] = (__bf16)b.z; v[7] = (__bf16)b.w;
  *(bf16x8*)dst = v;
}

// Coherent (agent-scope, sc0 sc1) 16B load of a bf16x8 fragment: bypasses the
// non-coherent L1/per-XCD-L2, reads straight from the coherent point.
__device__ __forceinline__ bf16x8 load_coh16(const __bf16* p) {
  union { unsigned long long u[2]; bf16x8 v; } r;
  r.u[0] = __hip_atomic_load((const unsigned long long*)p,     __ATOMIC_RELAXED, __HIP_MEMORY_SCOPE_AGENT);
  r.u[1] = __hip_atomic_load((const unsigned long long*)p + 1, __ATOMIC_RELAXED, __HIP_MEMORY_SCOPE_AGENT);
  return r.v;
}

// Coherent 2B bf16 store (write-through to the coherent point).
__device__ __forceinline__ void store_coh_bf16(__bf16* p, float v) {
  __bf16 b = (__bf16)v;
  unsigned short u;
  __builtin_memcpy(&u, &b, 2);
  __hip_atomic_store((unsigned short*)p, u, __ATOMIC_RELAXED, __HIP_MEMORY_SCOPE_AGENT);
}

// Parallel arrival detection: lane l polls producer (l&31)'s private flag line
// (128B apart -> no serialization anywhere). Exits when ALL producers >= tgt.
__device__ __forceinline__ void wait_flags(const unsigned* f, unsigned tgt) {
  const unsigned* p = f + (threadIdx.x & 31) * 32;   // 32 uints = 128B stride
  for (;;) {
    const unsigned v = __hip_atomic_load(p, __ATOMIC_RELAXED, __HIP_MEMORY_SCOPE_AGENT);
    if (__all((int)(v >= tgt))) break;
    __builtin_amdgcn_s_sleep(1);
  }
}

// f32 -> bf16 bulk convert, 8 elems/thread
__global__ __launch_bounds__(256) void cvt_f32_bf16(
    const float* __restrict__ s, __bf16* __restrict__ d, long n8)
{
  long i = (long)blockIdx.x * 256 + threadIdx.x;
  if (i >= n8) return;
  const float4* sp = (const float4*)s + i * 2;
  store_bf8(d + i * 8, sp[0], sp[1]);
}

// dst[r,:] = bf16(emb[idx[r],:]), rows of 512; one 64-thread block per row
__global__ __launch_bounds__(64) void gather_cvt(
    const float* __restrict__ emb, const int* __restrict__ idx, __bf16* __restrict__ dst)
{
  const int r = blockIdx.x;
  const long row = idx[r];
  const float4* sp = (const float4*)(emb + row * 512) + threadIdx.x * 2;
  store_bf8(dst + (long)r * 512 + threadIdx.x * 8, sp[0], sp[1]);
}

// ---------------------------------------------------------------------------
// GEMM: C[M,N] (fp32) = A[M,512](bf16) @ B[N,512](bf16)^T + bias[N](fp32)
// Block = 256 threads (4 waves), block tile 128(M) x 128(N), K=512.
// Wave w: rows m0+w*32 .. +32 (2 M-frags), all 128 N cols (8 N-frags).
// ---------------------------------------------------------------------------
__global__ __launch_bounds__(256) void gemm_bt(
    const __bf16* __restrict__ A, const __bf16* __restrict__ B,
    const float* __restrict__ bias, float* __restrict__ C, int M, int N)
{
  const int wave = threadIdx.x >> 6;
  const int lane = threadIdx.x & 63;
  const int l16 = lane & 15;
  const int quad = lane >> 4;

  const int m0 = blockIdx.x * 128 + wave * 32;
  const int n0 = blockIdx.y * 128;

  int r0 = m0 + l16;       if (r0 >= M) r0 = M - 1;
  int r1 = m0 + 16 + l16;  if (r1 >= M) r1 = M - 1;
  const __bf16* __restrict__ A0 = A + (long)r0 * 512 + quad * 8;
  const __bf16* __restrict__ A1 = A + (long)r1 * 512 + quad * 8;

  const __bf16* bp[8];
#pragma unroll
  for (int i = 0; i < 8; ++i)
    bp[i] = B + (long)(n0 + i * 16 + l16) * 512 + quad * 8;

  f32x4 acc[2][8];
#pragma unroll
  for (int mi = 0; mi < 2; ++mi)
#pragma unroll
    for (int i = 0; i < 8; ++i) acc[mi][i] = (f32x4){0.f, 0.f, 0.f, 0.f};

#pragma unroll
  for (int ks = 0; ks < 16; ++ks) {
    bf16x8 a0 = *(const bf16x8*)(A0 + ks * 32);
    bf16x8 a1 = *(const bf16x8*)(A1 + ks * 32);
#pragma unroll
    for (int i = 0; i < 8; ++i) {
      bf16x8 b = *(const bf16x8*)(bp[i] + ks * 32);
      acc[0][i] = __builtin_amdgcn_mfma_f32_16x16x32_bf16(a0, b, acc[0][i], 0, 0, 0);
      acc[1][i] = __builtin_amdgcn_mfma_f32_16x16x32_bf16(a1, b, acc[1][i], 0, 0, 0);
    }
  }

#pragma unroll
  for (int mi = 0; mi < 2; ++mi) {
    const int crow = m0 + mi * 16 + quad * 4;
#pragma unroll
    for (int i = 0; i < 8; ++i) {
      const int n = n0 + i * 16 + l16;
      const float bv = bias ? bias[n] : 0.0f;
#pragma unroll
      for (int r = 0; r < 4; ++r) {
        const int row = crow + r;
        if (row < M) C[(long)row * N + n] = acc[mi][i][r] + bv;
      }
    }
  }
}

// ---------------------------------------------------------------------------
// Pipelined 2-layer GRU recurrence. Grid = 64 WGs x 128 threads.
//   WGs  0..31 : layer 0 (GI precomputed in f32, (T,32,1536))
//   WGs 32..63 : layer 1 (computes gi = y0[t] @ Wih1^T on the fly via MFMA)
// WG c owns hidden cols [c*16, c*16+16). Per layer, h is exchanged through
// WRITE-ONCE timestep slots Y[t+1] (T+1 slots of 32x512 bf16) using relaxed
// agent-scope atomic stores/loads (sc0 sc1 -> coherent point).
// Arrival: per-WG flag word on a private 128B line (plain store, no RMW);
// detection: lane-parallel poll of all 32 producers, __all() exit.
// ---------------------------------------------------------------------------
__global__ __launch_bounds__(128) void gru2_pipe(
    const float* __restrict__ GI,
    const float* __restrict__ Whh0, const float* __restrict__ bhh0,
    const float* __restrict__ Wih1, const float* __restrict__ bih1,
    const float* __restrict__ Whh1, const float* __restrict__ bhh1,
    __bf16* __restrict__ Y0, __bf16* __restrict__ Y1,   // (T+1,32,512) slots
    const __bf16* __restrict__ h0i, const __bf16* __restrict__ h1i,
    float* __restrict__ hf0, float* __restrict__ hf1,   // 32x512 f32 masters
    unsigned* __restrict__ flags0, unsigned* __restrict__ flags1, int T)
{
  __shared__ __align__(16) __bf16 wh[48 * 520];  // Whh slice (own layer)
  __shared__ __align__(16) __bf16 wi[48 * 520];  // Wih1 slice (layer 1 only)

  const int tid = threadIdx.x;
  const int L   = blockIdx.x >> 5;
  const int c   = blockIdx.x & 31;
  const int w   = tid >> 6;
  const int lane = tid & 63;
  const int l16 = lane & 15;
  const int quad = lane >> 4;

  const float* __restrict__ Whh = L ? Whh1 : Whh0;
  const float* __restrict__ bhh = L ? bhh1 : bhh0;
  __bf16* __restrict__ Yown = L ? Y1 : Y0;
  const __bf16* __restrict__ hini = L ? h1i : h0i;
  float* __restrict__ hf = L ? hf1 : hf0;
  unsigned* __restrict__ fOwn = L ? flags1 : flags0;

  // Preload+convert Whh slice (and Wih1 slice for layer 1) into LDS.
  for (int ch = tid; ch < 48 * 64; ch += 128) {
    const int lr = ch >> 6, kc = ch & 63;
    const int g = lr >> 4, j = lr & 15;
    const float4* sp = (const float4*)(Whh + (long)(g * 512 + c * 16 + j) * 512) + kc * 2;
    store_bf8(&wh[lr * 520 + kc * 8], sp[0], sp[1]);
  }
  if (L) {
    for (int ch = tid; ch < 48 * 64; ch += 128) {
      const int lr = ch >> 6, kc = ch & 63;
      const int g = lr >> 4, j = lr & 15;
      const float4* sp = (const float4*)(Wih1 + (long)(g * 512 + c * 16 + j) * 512) + kc * 2;
      store_bf8(&wi[lr * 520 + kc * 8], sp[0], sp[1]);
    }
  }

  // Biases per output col (fused: r/z get bih+bhh on layer 1).
  float bR = bhh[0 * 512 + c * 16 + l16];
  float bZ = bhh[1 * 512 + c * 16 + l16];
  float bH = bhh[2 * 512 + c * 16 + l16];
  float bN = 0.f;
  if (L) {
    bR += bih1[0 * 512 + c * 16 + l16];
    bZ += bih1[1 * 512 + c * 16 + l16];
    bN  = bih1[2 * 512 + c * 16 + l16];
  }
  __syncthreads();

  // This thread's 4 output elements (MFMA C layout): rows b0..b0+3, col.
  const int b0  = w * 16 + quad * 4;
  const int col = c * 16 + l16;

  float hprev[4];
#pragma unroll
  for (int r = 0; r < 4; ++r) hprev[r] = hf[(b0 + r) * 512 + col];

  for (int t = 0; t < T; ++t) {
    // Early private loads (no cross-WG dependency): layer-0 gate inputs.
    float giR[4] = {0, 0, 0, 0}, giZ[4] = {0, 0, 0, 0}, giN[4] = {0, 0, 0, 0};
    if (!L) {
      const float* GIt = GI + (long)t * 49152;
#pragma unroll
      for (int r = 0; r < 4; ++r) {
        const float* gp = GIt + (b0 + r) * 1536 + col;
        giR[r] = gp[0];
        giZ[r] = gp[512];
        giN[r] = gp[1024];
      }
    }

    // Wait for producers (all lanes poll in parallel; no barrier needed —
    // each wave independently satisfies the same condition).
    if (L) {
      wait_flags(flags0, (unsigned)(t + 1));   // y0[t] ready
      if (t) wait_flags(flags1, (unsigned)t);  // own h1[t] ready
    } else if (t) {
      wait_flags(flags0, (unsigned)t);         // own h0[t] ready
    }

    // Issue ALL coherent fragment loads first, then MFMA.
    const __bf16* hsrc = t ? (Yown + (long)t * 16384) : hini;
    const __bf16* hA = hsrc + (w * 16 + l16) * 512 + quad * 8;
    bf16x8 ha[16], xa[16];
#pragma unroll
    for (int ks = 0; ks < 16; ++ks) ha[ks] = load_coh16(hA + ks * 32);
    if (L) {
      const __bf16* xA = Y0 + (long)(t + 1) * 16384 + (w * 16 + l16) * 512 + quad * 8;
#pragma unroll
      for (int ks = 0; ks < 16; ++ks) xa[ks] = load_coh16(xA + ks * 32);
    }

    f32x4 accR = {bR, bR, bR, bR};
    f32x4 accZ = {bZ, bZ, bZ, bZ};
    f32x4 accH = {bH, bH, bH, bH};
    f32x4 accN = {bN, bN, bN, bN};

#pragma unroll
    for (int ks = 0; ks < 16; ++ks) {
      const int o = ks * 32 + quad * 8;
      accR = __builtin_amdgcn_mfma_f32_16x16x32_bf16(ha[ks], *(const bf16x8*)&wh[(     l16) * 520 + o], accR, 0, 0, 0);
      accZ = __builtin_amdgcn_mfma_f32_16x16x32_bf16(ha[ks], *(const bf16x8*)&wh[(16 + l16) * 520 + o], accZ, 0, 0, 0);
      accH = __builtin_amdgcn_mfma_f32_16x16x32_bf16(ha[ks], *(const bf16x8*)&wh[(32 + l16) * 520 + o], accH, 0, 0, 0);
    }
    if (L) {
#pragma unroll
      for (int ks = 0; ks < 16; ++ks) {
        const int o = ks * 32 + quad * 8;
        accR = __builtin_amdgcn_mfma_f32_16x16x32_bf16(xa[ks], *(const bf16x8*)&wi[(     l16) * 520 + o], accR, 0, 0, 0);
        accZ = __builtin_amdgcn_mfma_f32_16x16x32_bf16(xa[ks], *(const bf16x8*)&wi[(16 + l16) * 520 + o], accZ, 0, 0, 0);
        accN = __builtin_amdgcn_mfma_f32_16x16x32_bf16(xa[ks], *(const bf16x8*)&wi[(32 + l16) * 520 + o], accN, 0, 0, 0);
      }
    }

    // Gates entirely in registers (C-fragment layout), coherent bf16 stores.
    __bf16* yout = Yown + (long)(t + 1) * 16384;
#pragma unroll
    for (int r = 0; r < 4; ++r) {
      float rs = accR[r], zs = accZ[r], hn = accH[r], nn = accN[r];
      if (!L) { rs += giR[r]; zs += giZ[r]; nn = giN[r]; }
      const float rg = 1.0f / (1.0f + expf(-rs));
      const float zg = 1.0f / (1.0f + expf(-zs));
      const float cand = tanhf(nn + rg * hn);
      const float hnew = (1.0f - zg) * cand + zg * hprev[r];
      hprev[r] = hnew;
      store_coh_bf16(yout + (b0 + r) * 512 + col, hnew);
    }

    // Per-thread store drain, WG-wide join, then one plain flag store.
    asm volatile("s_waitcnt vmcnt(0)" ::: "memory");
    __syncthreads();
    if (tid == 0)
      __hip_atomic_store(fOwn + c * 32, (unsigned)(t + 1),
                         __ATOMIC_RELAXED, __HIP_MEMORY_SCOPE_AGENT);
  }

  // Persist f32 master for the next stage (enc -> dec handoff).
#pragma unroll
  for (int r = 0; r < 4; ++r) hf[(b0 + r) * 512 + col] = hprev[r];
}

// ---------------------------------------------------------------------------
// Workspace layout (bytes), total ~59.7 MB:
//  GI    @ 0          12,582,912  (2048*1536 f32; reused enc0/dec0)
//  Xenc  @ 12,582,912  2,097,152
//  Xdec  @ 14,680,064  1,540,096
//  Y0e   @ 16,220,160  2,129,920  (65 slots: slot0 unused, 1..64 = y0 enc)
//  Y1e   @ 18,350,080  2,129,920  (slot 64 = enc layer1 final h)
//  Y0d   @ 20,480,000  1,572,864  (48 slots)
//  Y1d   @ 22,052,864  1,572,864  (slots 1..47 = D1 -> out GEMM A)
//  Wb0   @ 23,625,728  1,572,864  (enc_Wih0 bf16)
//  Wb2   @ 25,198,592  1,572,864  (dec_Wih0 bf16)
//  outWb @ 26,771,456 32,768,000
//  hf0   @ 59,539,456     65,536 ; hf1 @ 59,604,992 65,536
//  zb    @ 59,670,528     32,768  (bf16 zeros = initial h)
//  flags @ 59,703,296     16,384  (4 groups x 32 flags x 128B lines)
// ---------------------------------------------------------------------------
extern "C" void kernel_launch(void* const* d_in, const int* in_sizes, int n_in,
                              void* d_out, int out_size, void* d_ws, size_t ws_size,
                              hipStream_t stream)
{
  const int* src = (const int*)d_in[0];
  const int* trg = (const int*)d_in[1];
  const float* enc_emb  = (const float*)d_in[2];
  const float* enc_Wih0 = (const float*)d_in[3];
  const float* enc_Whh0 = (const float*)d_in[4];
  const float* enc_bih0 = (const float*)d_in[5];
  const float* enc_bhh0 = (const float*)d_in[6];
  const float* enc_Wih1 = (const float*)d_in[7];
  const float* enc_Whh1 = (const float*)d_in[8];
  const float* enc_bih1 = (const float*)d_in[9];
  const float* enc_bhh1 = (const float*)d_in[10];
  const float* dec_emb  = (const float*)d_in[11];
  const float* dec_Wih0 = (const float*)d_in[12];
  const float* dec_Whh0 = (const float*)d_in[13];
  const float* dec_bih0 = (const float*)d_in[14];
  const float* dec_bhh0 = (const float*)d_in[15];
  const float* dec_Wih1 = (const float*)d_in[16];
  const float* dec_Whh1 = (const float*)d_in[17];
  const float* dec_bih1 = (const float*)d_in[18];
  const float* dec_bhh1 = (const float*)d_in[19];
  const float* out_W    = (const float*)d_in[20];
  const float* out_b    = (const float*)d_in[21];

  char* ws = (char*)d_ws;
  float*  GI    = (float*)(ws + 0);
  __bf16* Xenc  = (__bf16*)(ws + 12582912);
  __bf16* Xdec  = (__bf16*)(ws + 14680064);
  __bf16* Y0e   = (__bf16*)(ws + 16220160);
  __bf16* Y1e   = (__bf16*)(ws + 18350080);
  __bf16* Y0d   = (__bf16*)(ws + 20480000);
  __bf16* Y1d   = (__bf16*)(ws + 22052864);
  __bf16* Wb0   = (__bf16*)(ws + 23625728);
  __bf16* Wb2   = (__bf16*)(ws + 25198592);
  __bf16* outWb = (__bf16*)(ws + 26771456);
  float*  hf0   = (float*)(ws + 59539456);
  float*  hf1   = (float*)(ws + 59604992);
  __bf16* zb    = (__bf16*)(ws + 59670528);
  unsigned* flags = (unsigned*)(ws + 59703296);   // 4 groups of 32x128B

  hipMemsetAsync(hf0, 0, 131072, stream);   // hf0 + hf1
  hipMemsetAsync(zb, 0, 32768, stream);
  hipMemsetAsync(flags, 0, 16384, stream);

  gather_cvt<<<2048, 64, 0, stream>>>(enc_emb, src, Xenc);
  gather_cvt<<<1504, 64, 0, stream>>>(dec_emb, trg, Xdec);   // rows 0..1503 = trg[:-1]
  cvt_f32_bf16<<<384, 256, 0, stream>>>(enc_Wih0, Wb0, 98304);
  cvt_f32_bf16<<<384, 256, 0, stream>>>(dec_Wih0, Wb2, 98304);
  cvt_f32_bf16<<<8000, 256, 0, stream>>>(out_W, outWb, 2048000);

  // encoder: GI for layer0, then both layers pipelined in one kernel
  gemm_bt<<<dim3(16, 12), 256, 0, stream>>>(Xenc, Wb0, enc_bih0, GI, 2048, 1536);
  gru2_pipe<<<64, 128, 0, stream>>>(GI, enc_Whh0, enc_bhh0,
                                    enc_Wih1, enc_bih1, enc_Whh1, enc_bhh1,
                                    Y0e, Y1e, zb, zb, hf0, hf1,
                                    flags + 0, flags + 1024, 64);
  // decoder: initial h = encoder finals (Y*e slot 64 bf16, hf* f32 in place)
  gemm_bt<<<dim3(12, 12), 256, 0, stream>>>(Xdec, Wb2, dec_bih0, GI, 1504, 1536);
  gru2_pipe<<<64, 128, 0, stream>>>(GI, dec_Whh0, dec_bhh0,
                                    dec_Wih1, dec_bih1, dec_Whh1, dec_bhh1,
                                    Y0d, Y1d, Y0e + 64 * 16384, Y1e + 64 * 16384, hf0, hf1,
                                    flags + 2048, flags + 3072, 47);

  // logits = D1 @ out_W^T + out_b  (D1 = Y1d slots 1..47, contiguous 1504x512)
  gemm_bt<<<dim3(12, 250), 256, 0, stream>>>(Y1d + 16384, outWb, out_b,
                                             (float*)d_out, 1504, 32000);
}

// Round 3
// 1298.689 us; speedup vs baseline: 2.2416x; 1.1016x over previous
//
#include <hip/hip_runtime.h>
#include <hip/hip_bf16.h>

typedef __bf16 bf16x8 __attribute__((ext_vector_type(8)));
typedef float  f32x4  __attribute__((ext_vector_type(4)));

__device__ __forceinline__ void store_bf8(__bf16* dst, float4 a, float4 b) {
  bf16x8 v;
  v[0] = (__bf16)a.x; v[1] = (__bf16)a.y; v[2] = (__bf16)a.z; v[3] = (__bf16)a.w;
  v[4] = (__bf16)b.x; v[5] = (__bf16)b.y; v[6] = (__bf16)b.z; v[7] = (__bf16)b.w;
  *(bf16x8*)dst = v;
}

// Coherent (agent-scope, sc0 sc1) 16B load of a bf16x8 fragment: bypasses the
// non-coherent L1/per-XCD-L2. Compiler-tracked (vmcnt handled for us).
__device__ __forceinline__ bf16x8 load_coh16(const __bf16* p) {
  union { unsigned long long u[2]; bf16x8 v; } r;
  r.u[0] = __hip_atomic_load((const unsigned long long*)p,     __ATOMIC_RELAXED, __HIP_MEMORY_SCOPE_AGENT);
  r.u[1] = __hip_atomic_load((const unsigned long long*)p + 1, __ATOMIC_RELAXED, __HIP_MEMORY_SCOPE_AGENT);
  return r.v;
}

// Coherent 16B store (write-through past L1/L2). Stores read their operands at
// issue -> no register-fill hazard, safe as inline asm. Ordered vs the drain
// below via "memory" clobbers.
__device__ __forceinline__ void store_coh16B(__bf16* p, bf16x8 v) {
  asm volatile("global_store_dwordx4 %0, %1, off sc0 sc1"
               :: "v"(p), "v"(v) : "memory");
}

// Parallel arrival detection: lane l polls producer (l&31)'s private flag line
// (128B apart -> no serialization anywhere). Exits when ALL producers >= tgt.
__device__ __forceinline__ void wait_flags(const unsigned* f, unsigned tgt) {
  const unsigned* p = f + (threadIdx.x & 31) * 32;   // 32 uints = 128B stride
  for (;;) {
    const unsigned v = __hip_atomic_load(p, __ATOMIC_RELAXED, __HIP_MEMORY_SCOPE_AGENT);
    if (__all((int)(v >= tgt))) break;
    __builtin_amdgcn_s_sleep(1);
  }
}

// f32 -> bf16 bulk convert, 8 elems/thread
__global__ __launch_bounds__(256) void cvt_f32_bf16(
    const float* __restrict__ s, __bf16* __restrict__ d, long n8)
{
  long i = (long)blockIdx.x * 256 + threadIdx.x;
  if (i >= n8) return;
  const float4* sp = (const float4*)s + i * 2;
  store_bf8(d + i * 8, sp[0], sp[1]);
}

// dst[r,:] = bf16(emb[idx[r],:]), rows of 512; one 64-thread block per row
__global__ __launch_bounds__(64) void gather_cvt(
    const float* __restrict__ emb, const int* __restrict__ idx, __bf16* __restrict__ dst)
{
  const int r = blockIdx.x;
  const long row = idx[r];
  const float4* sp = (const float4*)(emb + row * 512) + threadIdx.x * 2;
  store_bf8(dst + (long)r * 512 + threadIdx.x * 8, sp[0], sp[1]);
}

// ---------------------------------------------------------------------------
// GEMM: C[M,N] (fp32) = A[M,512](bf16) @ B[N,512](bf16)^T + bias[N](fp32)
// Block = 256 threads (4 waves), block tile 128(M) x 128(N), K=512.
// ---------------------------------------------------------------------------
__global__ __launch_bounds__(256) void gemm_bt(
    const __bf16* __restrict__ A, const __bf16* __restrict__ B,
    const float* __restrict__ bias, float* __restrict__ C, int M, int N)
{
  const int wave = threadIdx.x >> 6;
  const int lane = threadIdx.x & 63;
  const int l16 = lane & 15;
  const int quad = lane >> 4;

  const int m0 = blockIdx.x * 128 + wave * 32;
  const int n0 = blockIdx.y * 128;

  int r0 = m0 + l16;       if (r0 >= M) r0 = M - 1;
  int r1 = m0 + 16 + l16;  if (r1 >= M) r1 = M - 1;
  const __bf16* __restrict__ A0 = A + (long)r0 * 512 + quad * 8;
  const __bf16* __restrict__ A1 = A + (long)r1 * 512 + quad * 8;

  const __bf16* bp[8];
#pragma unroll
  for (int i = 0; i < 8; ++i)
    bp[i] = B + (long)(n0 + i * 16 + l16) * 512 + quad * 8;

  f32x4 acc[2][8];
#pragma unroll
  for (int mi = 0; mi < 2; ++mi)
#pragma unroll
    for (int i = 0; i < 8; ++i) acc[mi][i] = (f32x4){0.f, 0.f, 0.f, 0.f};

#pragma unroll
  for (int ks = 0; ks < 16; ++ks) {
    bf16x8 a0 = *(const bf16x8*)(A0 + ks * 32);
    bf16x8 a1 = *(const bf16x8*)(A1 + ks * 32);
#pragma unroll
    for (int i = 0; i < 8; ++i) {
      bf16x8 b = *(const bf16x8*)(bp[i] + ks * 32);
      acc[0][i] = __builtin_amdgcn_mfma_f32_16x16x32_bf16(a0, b, acc[0][i], 0, 0, 0);
      acc[1][i] = __builtin_amdgcn_mfma_f32_16x16x32_bf16(a1, b, acc[1][i], 0, 0, 0);
    }
  }

#pragma unroll
  for (int mi = 0; mi < 2; ++mi) {
    const int crow = m0 + mi * 16 + quad * 4;
#pragma unroll
    for (int i = 0; i < 8; ++i) {
      const int n = n0 + i * 16 + l16;
      const float bv = bias ? bias[n] : 0.0f;
#pragma unroll
      for (int r = 0; r < 4; ++r) {
        const int row = crow + r;
        if (row < M) C[(long)row * N + n] = acc[mi][i][r] + bv;
      }
    }
  }
}

// ---------------------------------------------------------------------------
// Pipelined 2-layer GRU recurrence. Grid = 64 WGs x 128 threads.
//   WGs  0..31 : layer 0 (GI precomputed in f32, (T,32,1536))
//   WGs 32..63 : layer 1 (computes gi = y0[t] @ Wih1^T on the fly via MFMA)
// WG c owns hidden cols [c*16, c*16+16). h exchanged through WRITE-ONCE
// timestep slots Y[t+1] via agent-scope accesses (sc0 sc1 -> coherent point).
// Store side: C-fragment transposed through 1KB LDS -> 64 x 16B coherent
// stores per WG per step (was 512 x 2B). Layer 1 runs its Wih1 half (xa)
// BEFORE waiting on its own h1 flag -> off the recurrence-critical path.
// ---------------------------------------------------------------------------
__global__ __launch_bounds__(128) void gru2_pipe(
    const float* __restrict__ GI,
    const float* __restrict__ Whh0, const float* __restrict__ bhh0,
    const float* __restrict__ Wih1, const float* __restrict__ bih1,
    const float* __restrict__ Whh1, const float* __restrict__ bhh1,
    __bf16* __restrict__ Y0, __bf16* __restrict__ Y1,   // (T+1,32,512) slots
    const __bf16* __restrict__ h0i, const __bf16* __restrict__ h1i,
    float* __restrict__ hf0, float* __restrict__ hf1,   // 32x512 f32 masters
    unsigned* __restrict__ flags0, unsigned* __restrict__ flags1, int T)
{
  __shared__ __align__(16) __bf16 wh[48 * 520];  // Whh slice (own layer)
  __shared__ __align__(16) __bf16 wi[48 * 520];  // Wih1 slice (layer 1 only)
  __shared__ __align__(16) __bf16 hlds[32][16];  // C-fragment transpose buffer

  const int tid = threadIdx.x;
  const int L   = blockIdx.x >> 5;
  const int c   = blockIdx.x & 31;
  const int w   = tid >> 6;
  const int lane = tid & 63;
  const int l16 = lane & 15;
  const int quad = lane >> 4;

  const float* __restrict__ Whh = L ? Whh1 : Whh0;
  const float* __restrict__ bhh = L ? bhh1 : bhh0;
  __bf16* __restrict__ Yown = L ? Y1 : Y0;
  const __bf16* __restrict__ hini = L ? h1i : h0i;
  float* __restrict__ hf = L ? hf1 : hf0;
  unsigned* __restrict__ fOwn = L ? flags1 : flags0;

  // Preload+convert Whh slice (and Wih1 slice for layer 1) into LDS.
  for (int ch = tid; ch < 48 * 64; ch += 128) {
    const int lr = ch >> 6, kc = ch & 63;
    const int g = lr >> 4, j = lr & 15;
    const float4* sp = (const float4*)(Whh + (long)(g * 512 + c * 16 + j) * 512) + kc * 2;
    store_bf8(&wh[lr * 520 + kc * 8], sp[0], sp[1]);
  }
  if (L) {
    for (int ch = tid; ch < 48 * 64; ch += 128) {
      const int lr = ch >> 6, kc = ch & 63;
      const int g = lr >> 4, j = lr & 15;
      const float4* sp = (const float4*)(Wih1 + (long)(g * 512 + c * 16 + j) * 512) + kc * 2;
      store_bf8(&wi[lr * 520 + kc * 8], sp[0], sp[1]);
    }
  }

  // Biases per output col (fused: r/z get bih+bhh on layer 1).
  float bR = bhh[0 * 512 + c * 16 + l16];
  float bZ = bhh[1 * 512 + c * 16 + l16];
  float bH = bhh[2 * 512 + c * 16 + l16];
  float bN = 0.f;
  if (L) {
    bR += bih1[0 * 512 + c * 16 + l16];
    bZ += bih1[1 * 512 + c * 16 + l16];
    bN  = bih1[2 * 512 + c * 16 + l16];
  }
  __syncthreads();

  // This thread's 4 output elements (MFMA C layout): rows b0..b0+3, col.
  const int b0  = w * 16 + quad * 4;
  const int col = c * 16 + l16;

  float hprev[4];
#pragma unroll
  for (int r = 0; r < 4; ++r) hprev[r] = hf[(b0 + r) * 512 + col];

  for (int t = 0; t < T; ++t) {
    // Early private loads (no cross-WG dependency): layer-0 gate inputs.
    float giR[4] = {0, 0, 0, 0}, giZ[4] = {0, 0, 0, 0}, giN[4] = {0, 0, 0, 0};
    if (!L) {
      const float* GIt = GI + (long)t * 49152;
#pragma unroll
      for (int r = 0; r < 4; ++r) {
        const float* gp = GIt + (b0 + r) * 1536 + col;
        giR[r] = gp[0];
        giZ[r] = gp[512];
        giN[r] = gp[1024];
      }
    }

    f32x4 accR = {bR, bR, bR, bR};
    f32x4 accZ = {bZ, bZ, bZ, bZ};
    f32x4 accH = {bH, bH, bH, bH};
    f32x4 accN = {bN, bN, bN, bN};

    // Layer 1: y0[t] half first (usually ready before our own h1 flag).
    if (L) {
      wait_flags(flags0, (unsigned)(t + 1));
      const __bf16* xA = Y0 + (long)(t + 1) * 16384 + (w * 16 + l16) * 512 + quad * 8;
      bf16x8 xa[16];
#pragma unroll
      for (int ks = 0; ks < 16; ++ks) xa[ks] = load_coh16(xA + ks * 32);
#pragma unroll
      for (int ks = 0; ks < 16; ++ks) {
        const int o = ks * 32 + quad * 8;
        accR = __builtin_amdgcn_mfma_f32_16x16x32_bf16(xa[ks], *(const bf16x8*)&wi[(     l16) * 520 + o], accR, 0, 0, 0);
        accZ = __builtin_amdgcn_mfma_f32_16x16x32_bf16(xa[ks], *(const bf16x8*)&wi[(16 + l16) * 520 + o], accZ, 0, 0, 0);
        accN = __builtin_amdgcn_mfma_f32_16x16x32_bf16(xa[ks], *(const bf16x8*)&wi[(32 + l16) * 520 + o], accN, 0, 0, 0);
      }
      if (t) wait_flags(flags1, (unsigned)t);
    } else if (t) {
      wait_flags(flags0, (unsigned)t);
    }

    // Own-layer h[t] half (the recurrence-critical chain).
    const __bf16* hsrc = t ? (Yown + (long)t * 16384) : hini;
    const __bf16* hA = hsrc + (w * 16 + l16) * 512 + quad * 8;
    bf16x8 ha[16];
#pragma unroll
    for (int ks = 0; ks < 16; ++ks) ha[ks] = load_coh16(hA + ks * 32);
#pragma unroll
    for (int ks = 0; ks < 16; ++ks) {
      const int o = ks * 32 + quad * 8;
      accR = __builtin_amdgcn_mfma_f32_16x16x32_bf16(ha[ks], *(const bf16x8*)&wh[(     l16) * 520 + o], accR, 0, 0, 0);
      accZ = __builtin_amdgcn_mfma_f32_16x16x32_bf16(ha[ks], *(const bf16x8*)&wh[(16 + l16) * 520 + o], accZ, 0, 0, 0);
      accH = __builtin_amdgcn_mfma_f32_16x16x32_bf16(ha[ks], *(const bf16x8*)&wh[(32 + l16) * 520 + o], accH, 0, 0, 0);
    }

    // Gates in registers (fast intrinsics), result -> LDS transpose buffer.
#pragma unroll
    for (int r = 0; r < 4; ++r) {
      float rs = accR[r], zs = accZ[r], hn = accH[r], nn = accN[r];
      if (!L) { rs += giR[r]; zs += giZ[r]; nn = giN[r]; }
      const float rg = __fdividef(1.0f, 1.0f + __expf(-rs));
      const float zg = __fdividef(1.0f, 1.0f + __expf(-zs));
      const float a2 = nn + rg * hn;
      const float e2 = __expf(2.0f * a2);
      const float cand = 1.0f - __fdividef(2.0f, e2 + 1.0f);   // tanh(a2)
      const float hnew = (1.0f - zg) * cand + zg * hprev[r];
      hprev[r] = hnew;
      hlds[b0 + r][l16] = (__bf16)hnew;
    }
    __syncthreads();

    // 64 x 16B coherent stores of the WG's 32x16 slice.
    __bf16* yout = Yown + (long)(t + 1) * 16384;
    if (tid < 64) {
      const int row = tid >> 1, half = tid & 1;
      bf16x8 hv = *(const bf16x8*)&hlds[row][half * 8];
      store_coh16B(yout + (long)row * 512 + c * 16 + half * 8, hv);
    }
    asm volatile("s_waitcnt vmcnt(0)" ::: "memory");
    __syncthreads();
    if (tid == 0)
      __hip_atomic_store(fOwn + c * 32, (unsigned)(t + 1),
                         __ATOMIC_RELAXED, __HIP_MEMORY_SCOPE_AGENT);
  }

  // Persist f32 master for the next stage (enc -> dec handoff, kernel-boundary
  // flush makes plain stores safe).
#pragma unroll
  for (int r = 0; r < 4; ++r) hf[(b0 + r) * 512 + col] = hprev[r];
}

// ---------------------------------------------------------------------------
// Workspace layout (bytes), total ~59.7 MB:
//  GI    @ 0          12,582,912  (2048*1536 f32; reused enc0/dec0)
//  Xenc  @ 12,582,912  2,097,152
//  Xdec  @ 14,680,064  1,540,096
//  Y0e   @ 16,220,160  2,129,920  (65 slots: slot0 unused, 1..64 = y0 enc)
//  Y1e   @ 18,350,080  2,129,920  (slot 64 = enc layer1 final h)
//  Y0d   @ 20,480,000  1,572,864  (48 slots)
//  Y1d   @ 22,052,864  1,572,864  (slots 1..47 = D1 -> out GEMM A)
//  Wb0   @ 23,625,728  1,572,864  (enc_Wih0 bf16)
//  Wb2   @ 25,198,592  1,572,864  (dec_Wih0 bf16)
//  outWb @ 26,771,456 32,768,000
//  hf0   @ 59,539,456     65,536 ; hf1 @ 59,604,992 65,536
//  zb    @ 59,670,528     32,768  (bf16 zeros = initial h)
//  flags @ 59,703,296     16,384  (4 groups x 32 flags x 128B lines)
// ---------------------------------------------------------------------------
extern "C" void kernel_launch(void* const* d_in, const int* in_sizes, int n_in,
                              void* d_out, int out_size, void* d_ws, size_t ws_size,
                              hipStream_t stream)
{
  const int* src = (const int*)d_in[0];
  const int* trg = (const int*)d_in[1];
  const float* enc_emb  = (const float*)d_in[2];
  const float* enc_Wih0 = (const float*)d_in[3];
  const float* enc_Whh0 = (const float*)d_in[4];
  const float* enc_bih0 = (const float*)d_in[5];
  const float* enc_bhh0 = (const float*)d_in[6];
  const float* enc_Wih1 = (const float*)d_in[7];
  const float* enc_Whh1 = (const float*)d_in[8];
  const float* enc_bih1 = (const float*)d_in[9];
  const float* enc_bhh1 = (const float*)d_in[10];
  const float* dec_emb  = (const float*)d_in[11];
  const float* dec_Wih0 = (const float*)d_in[12];
  const float* dec_Whh0 = (const float*)d_in[13];
  const float* dec_bih0 = (const float*)d_in[14];
  const float* dec_bhh0 = (const float*)d_in[15];
  const float* dec_Wih1 = (const float*)d_in[16];
  const float* dec_Whh1 = (const float*)d_in[17];
  const float* dec_bih1 = (const float*)d_in[18];
  const float* dec_bhh1 = (const float*)d_in[19];
  const float* out_W    = (const float*)d_in[20];
  const float* out_b    = (const float*)d_in[21];

  char* ws = (char*)d_ws;
  float*  GI    = (float*)(ws + 0);
  __bf16* Xenc  = (__bf16*)(ws + 12582912);
  __bf16* Xdec  = (__bf16*)(ws + 14680064);
  __bf16* Y0e   = (__bf16*)(ws + 16220160);
  __bf16* Y1e   = (__bf16*)(ws + 18350080);
  __bf16* Y0d   = (__bf16*)(ws + 20480000);
  __bf16* Y1d   = (__bf16*)(ws + 22052864);
  __bf16* Wb0   = (__bf16*)(ws + 23625728);
  __bf16* Wb2   = (__bf16*)(ws + 25198592);
  __bf16* outWb = (__bf16*)(ws + 26771456);
  float*  hf0   = (float*)(ws + 59539456);
  float*  hf1   = (float*)(ws + 59604992);
  __bf16* zb    = (__bf16*)(ws + 59670528);
  unsigned* flags = (unsigned*)(ws + 59703296);   // 4 groups of 32x128B

  hipMemsetAsync(hf0, 0, 131072, stream);   // hf0 + hf1
  hipMemsetAsync(zb, 0, 32768, stream);
  hipMemsetAsync(flags, 0, 16384, stream);

  gather_cvt<<<2048, 64, 0, stream>>>(enc_emb, src, Xenc);
  gather_cvt<<<1504, 64, 0, stream>>>(dec_emb, trg, Xdec);   // rows 0..1503 = trg[:-1]
  cvt_f32_bf16<<<384, 256, 0, stream>>>(enc_Wih0, Wb0, 98304);
  cvt_f32_bf16<<<384, 256, 0, stream>>>(dec_Wih0, Wb2, 98304);
  cvt_f32_bf16<<<8000, 256, 0, stream>>>(out_W, outWb, 2048000);

  // encoder: GI for layer0, then both layers pipelined in one kernel
  gemm_bt<<<dim3(16, 12), 256, 0, stream>>>(Xenc, Wb0, enc_bih0, GI, 2048, 1536);
  gru2_pipe<<<64, 128, 0, stream>>>(GI, enc_Whh0, enc_bhh0,
                                    enc_Wih1, enc_bih1, enc_Whh1, enc_bhh1,
                                    Y0e, Y1e, zb, zb, hf0, hf1,
                                    flags + 0, flags + 1024, 64);
  // decoder: initial h = encoder finals (Y*e slot 64 bf16, hf* f32 in place)
  gemm_bt<<<dim3(12, 12), 256, 0, stream>>>(Xdec, Wb2, dec_bih0, GI, 1504, 1536);
  gru2_pipe<<<64, 128, 0, stream>>>(GI, dec_Whh0, dec_bhh0,
                                    dec_Wih1, dec_bih1, dec_Whh1, dec_bhh1,
                                    Y0d, Y1d, Y0e + 64 * 16384, Y1e + 64 * 16384, hf0, hf1,
                                    flags + 2048, flags + 3072, 47);

  // logits = D1 @ out_W^T + out_b  (D1 = Y1d slots 1..47, contiguous 1504x512)
  gemm_bt<<<dim3(12, 250), 256, 0, stream>>>(Y1d + 16384, outWb, out_b,
                                             (float*)d_out, 1504, 32000);
}

// Round 5
// 1235.158 us; speedup vs baseline: 2.3569x; 1.0514x over previous
//
#include <hip/hip_runtime.h>
#include <hip/hip_bf16.h>

typedef __bf16 bf16x8 __attribute__((ext_vector_type(8)));
typedef float  f32x4  __attribute__((ext_vector_type(4)));

__device__ __forceinline__ void store_bf8(__bf16* dst, float4 a, float4 b) {
  bf16x8 v;
  v[0] = (__bf16)a.x; v[1] = (__bf16)a.y; v[2] = (__bf16)a.z; v[3] = (__bf16)a.w;
  v[4] = (__bf16)b.x; v[5] = (__bf16)b.y; v[6] = (__bf16)b.z; v[7] = (__bf16)b.w;
  *(bf16x8*)dst = v;
}

// Per-wave arrival detection: lane l polls producer ((l&31), w)'s private
// 128B flag line. Exits when ALL 32 producers of wave-slot w reach tgt.
// Trailing compiler fence keeps subsequent plain loads from hoisting.
__device__ __forceinline__ void wait_flags_w(const unsigned* f, int w, unsigned tgt) {
  const unsigned* p = f + ((((threadIdx.x & 31) << 1) + w) << 5);
  for (;;) {
    const unsigned v = __hip_atomic_load(p, __ATOMIC_RELAXED, __HIP_MEMORY_SCOPE_AGENT);
    if (__all((int)(v >= tgt))) break;
    __builtin_amdgcn_s_sleep(1);
  }
  asm volatile("" ::: "memory");
}

// f32 -> bf16 bulk convert, 8 elems/thread
__global__ __launch_bounds__(256) void cvt_f32_bf16(
    const float* __restrict__ s, __bf16* __restrict__ d, long n8)
{
  long i = (long)blockIdx.x * 256 + threadIdx.x;
  if (i >= n8) return;
  const float4* sp = (const float4*)s + i * 2;
  store_bf8(d + i * 8, sp[0], sp[1]);
}

// dst[r,:] = bf16(emb[idx[r],:]), rows of 512; one 64-thread block per row
__global__ __launch_bounds__(64) void gather_cvt(
    const float* __restrict__ emb, const int* __restrict__ idx, __bf16* __restrict__ dst)
{
  const int r = blockIdx.x;
  const long row = idx[r];
  const float4* sp = (const float4*)(emb + row * 512) + threadIdx.x * 2;
  store_bf8(dst + (long)r * 512 + threadIdx.x * 8, sp[0], sp[1]);
}

// ---------------------------------------------------------------------------
// LDS-tiled GEMM (plain HIP reg-staging, no exotic builtins):
// C[M,N](f32) = A[M,512](bf16) @ B[N,512](bf16)^T + bias[N].
// 256 threads / 4 waves, tile 128(M) x 128(N), K-step 64 (8 iters).
// LDS [128 rows][8 chunks of 16B], chunk slot = ch ^ (row&7) (XOR swizzle);
// ds_read uses the same involution -> conflict-free b128 reads.
// Next K-step's global loads issued before the compute barrier (prefetch).
// 1-D grid with XCD-aware swizzle when nwg % 8 == 0.
// ---------------------------------------------------------------------------
__global__ __launch_bounds__(256) void gemm_tile(
    const __bf16* __restrict__ A, const __bf16* __restrict__ B,
    const float* __restrict__ bias, float* __restrict__ C,
    int M, int N, int NT)
{
  __shared__ __align__(16) __bf16 sA[128 * 64];
  __shared__ __align__(16) __bf16 sB[128 * 64];

  const int nwg = gridDim.x;
  const int bid = blockIdx.x;
  const int swz = (nwg & 7) ? bid : ((bid & 7) * (nwg >> 3) + (bid >> 3));
  const int m0 = (swz / NT) * 128;
  const int n0 = (swz % NT) * 128;

  const int tid  = threadIdx.x;
  const int wave = tid >> 6;
  const int lane = tid & 63;
  const int l16  = lane & 15;
  const int quad = lane >> 4;

  // Staging map: sweep s covers 16B-chunk index e = s*256+tid of the tile.
  int srow[4], sch[4];
  const __bf16* ga[4];
  const __bf16* gb[4];
#pragma unroll
  for (int s = 0; s < 4; ++s) {
    const int e = s * 256 + tid;
    srow[s] = e >> 3;
    sch[s]  = e & 7;
    int ra = m0 + srow[s]; if (ra >= M) ra = M - 1;
    ga[s] = A + (long)ra * 512 + sch[s] * 8;
    gb[s] = B + (long)(n0 + srow[s]) * 512 + sch[s] * 8;   // N % 128 == 0
  }

  f32x4 acc[2][8];
#pragma unroll
  for (int mi = 0; mi < 2; ++mi)
#pragma unroll
    for (int i = 0; i < 8; ++i) acc[mi][i] = (f32x4){0.f, 0.f, 0.f, 0.f};

  bf16x8 aval[4], bval[4];
#pragma unroll
  for (int s = 0; s < 4; ++s) {
    aval[s] = *(const bf16x8*)(ga[s]);
    bval[s] = *(const bf16x8*)(gb[s]);
  }

  for (int k0 = 0; k0 < 512; k0 += 64) {
    __syncthreads();   // previous compute done -> LDS free
#pragma unroll
    for (int s = 0; s < 4; ++s) {
      const int slot = (sch[s] ^ (srow[s] & 7)) << 3;
      *(bf16x8*)&sA[srow[s] * 64 + slot] = aval[s];
      *(bf16x8*)&sB[srow[s] * 64 + slot] = bval[s];
    }
    if (k0 + 64 < 512) {
#pragma unroll
      for (int s = 0; s < 4; ++s) {    // prefetch next K-step (overlaps MFMA)
        aval[s] = *(const bf16x8*)(ga[s] + k0 + 64);
        bval[s] = *(const bf16x8*)(gb[s] + k0 + 64);
      }
    }
    __syncthreads();   // staging visible

#pragma unroll
    for (int ks = 0; ks < 2; ++ks) {
      const int ck = (((ks * 4 + quad) ^ (l16 & 7)) << 3);   // elem offset
      bf16x8 a0 = *(const bf16x8*)&sA[(wave * 32 +      l16) * 64 + ck];
      bf16x8 a1 = *(const bf16x8*)&sA[(wave * 32 + 16 + l16) * 64 + ck];
#pragma unroll
      for (int i = 0; i < 8; ++i) {
        bf16x8 b = *(const bf16x8*)&sB[(i * 16 + l16) * 64 + ck];
        acc[0][i] = __builtin_amdgcn_mfma_f32_16x16x32_bf16(a0, b, acc[0][i], 0, 0, 0);
        acc[1][i] = __builtin_amdgcn_mfma_f32_16x16x32_bf16(a1, b, acc[1][i], 0, 0, 0);
      }
    }
  }

#pragma unroll
  for (int mi = 0; mi < 2; ++mi) {
    const int crow = m0 + wave * 32 + mi * 16 + quad * 4;
#pragma unroll
    for (int i = 0; i < 8; ++i) {
      const int n = n0 + i * 16 + l16;
      const float bv = bias ? bias[n] : 0.0f;
#pragma unroll
      for (int r = 0; r < 4; ++r) {
        const int row = crow + r;
        if (row < M) C[(long)row * N + n] = acc[mi][i][r] + bv;
      }
    }
  }
}

// ---------------------------------------------------------------------------
// Pipelined 2-layer GRU recurrence. Grid = 64 WGs x 128 threads.
//   WGs  0..31 : layer 0 (GI precomputed in f32, (T,32,1536))
//   WGs 32..63 : layer 1 (computes gi = y0[t] @ Wih1^T on the fly via MFMA)
// WG c owns hidden cols [c*16, c*16+16). h exchanged through WRITE-ONCE
// timestep slots Y[t+1]. Producers store coherently (sc0 sc1 -> L3) and
// publish a per-(WG,wave) flag; consumers read the write-once data with
// PLAIN CACHED loads (no cache can hold a pre-write copy of a line nobody
// touched before the coherent write; dispatch boundaries handle reuse).
// Each wave is an independent agent: stores only its own 16 batch rows,
// waits only on its wave-slot's 32 producer flags -> NO __syncthreads in
// the step loop.
// ---------------------------------------------------------------------------
__global__ __launch_bounds__(128) void gru2_pipe(
    const float* __restrict__ GI,
    const float* __restrict__ Whh0, const float* __restrict__ bhh0,
    const float* __restrict__ Wih1, const float* __restrict__ bih1,
    const float* __restrict__ Whh1, const float* __restrict__ bhh1,
    __bf16* __restrict__ Y0, __bf16* __restrict__ Y1,   // (T+1,32,512) slots
    const __bf16* __restrict__ h0i, const __bf16* __restrict__ h1i,
    float* __restrict__ hf0, float* __restrict__ hf1,   // 32x512 f32 masters
    unsigned* __restrict__ flags0, unsigned* __restrict__ flags1, int T)
{
  __shared__ __align__(16) __bf16 wh[48 * 520];  // Whh slice (own layer)
  __shared__ __align__(16) __bf16 wi[48 * 520];  // Wih1 slice (layer 1 only)
  __shared__ __align__(16) __bf16 hlds[32][16];  // per-wave transpose buffer

  const int tid = threadIdx.x;
  const int L   = blockIdx.x >> 5;
  const int c   = blockIdx.x & 31;
  const int w   = tid >> 6;
  const int lane = tid & 63;
  const int l16 = lane & 15;
  const int quad = lane >> 4;

  const float* __restrict__ Whh = L ? Whh1 : Whh0;
  const float* __restrict__ bhh = L ? bhh1 : bhh0;
  __bf16* __restrict__ Yown = L ? Y1 : Y0;
  const __bf16* __restrict__ hini = L ? h1i : h0i;
  float* __restrict__ hf = L ? hf1 : hf0;
  unsigned* __restrict__ fOwn = L ? flags1 : flags0;

  // Preload+convert Whh slice (and Wih1 slice for layer 1) into LDS.
  for (int ch = tid; ch < 48 * 64; ch += 128) {
    const int lr = ch >> 6, kc = ch & 63;
    const int g = lr >> 4, j = lr & 15;
    const float4* sp = (const float4*)(Whh + (long)(g * 512 + c * 16 + j) * 512) + kc * 2;
    store_bf8(&wh[lr * 520 + kc * 8], sp[0], sp[1]);
  }
  if (L) {
    for (int ch = tid; ch < 48 * 64; ch += 128) {
      const int lr = ch >> 6, kc = ch & 63;
      const int g = lr >> 4, j = lr & 15;
      const float4* sp = (const float4*)(Wih1 + (long)(g * 512 + c * 16 + j) * 512) + kc * 2;
      store_bf8(&wi[lr * 520 + kc * 8], sp[0], sp[1]);
    }
  }

  // Biases per output col (fused: r/z get bih+bhh on layer 1).
  float bR = bhh[0 * 512 + c * 16 + l16];
  float bZ = bhh[1 * 512 + c * 16 + l16];
  float bH = bhh[2 * 512 + c * 16 + l16];
  float bN = 0.f;
  if (L) {
    bR += bih1[0 * 512 + c * 16 + l16];
    bZ += bih1[1 * 512 + c * 16 + l16];
    bN  = bih1[2 * 512 + c * 16 + l16];
  }
  __syncthreads();

  // This thread's 4 output elements (MFMA C layout): rows b0..b0+3, col.
  const int b0  = w * 16 + quad * 4;
  const int col = c * 16 + l16;
  // Store mapping: lane stores 8B (4 cols) of row srow (own wave's rows).
  const int srow = w * 16 + (lane >> 2);
  const int sch4 = (lane & 3) * 4;

  float hprev[4];
#pragma unroll
  for (int r = 0; r < 4; ++r) hprev[r] = hf[(b0 + r) * 512 + col];

  for (int t = 0; t < T; ++t) {
    // Early private loads (no cross-WG dependency): layer-0 gate inputs.
    float giR[4] = {0, 0, 0, 0}, giZ[4] = {0, 0, 0, 0}, giN[4] = {0, 0, 0, 0};
    if (!L) {
      const float* GIt = GI + (long)t * 49152;
#pragma unroll
      for (int r = 0; r < 4; ++r) {
        const float* gp = GIt + (b0 + r) * 1536 + col;
        giR[r] = gp[0];
        giZ[r] = gp[512];
        giN[r] = gp[1024];
      }
    }

    f32x4 accR = {bR, bR, bR, bR};
    f32x4 accZ = {bZ, bZ, bZ, bZ};
    f32x4 accH = {bH, bH, bH, bH};
    f32x4 accN = {bN, bN, bN, bN};

    // Layer 1: y0[t] half first (usually ready before our own h1 flag).
    if (L) {
      wait_flags_w(flags0, w, (unsigned)(t + 1));
      const __bf16* xA = Y0 + (long)(t + 1) * 16384 + (w * 16 + l16) * 512 + quad * 8;
      bf16x8 xa[16];
#pragma unroll
      for (int ks = 0; ks < 16; ++ks) xa[ks] = *(const bf16x8*)(xA + ks * 32);
#pragma unroll
      for (int ks = 0; ks < 16; ++ks) {
        const int o = ks * 32 + quad * 8;
        accR = __builtin_amdgcn_mfma_f32_16x16x32_bf16(xa[ks], *(const bf16x8*)&wi[(     l16) * 520 + o], accR, 0, 0, 0);
        accZ = __builtin_amdgcn_mfma_f32_16x16x32_bf16(xa[ks], *(const bf16x8*)&wi[(16 + l16) * 520 + o], accZ, 0, 0, 0);
        accN = __builtin_amdgcn_mfma_f32_16x16x32_bf16(xa[ks], *(const bf16x8*)&wi[(32 + l16) * 520 + o], accN, 0, 0, 0);
      }
      if (t) wait_flags_w(flags1, w, (unsigned)t);
    } else if (t) {
      wait_flags_w(flags0, w, (unsigned)t);
    }

    // Own-layer h[t] half (recurrence-critical). Plain cached loads.
    const __bf16* hsrc = t ? (Yown + (long)t * 16384) : hini;
    const __bf16* hA = hsrc + (w * 16 + l16) * 512 + quad * 8;
    bf16x8 ha[16];
#pragma unroll
    for (int ks = 0; ks < 16; ++ks) ha[ks] = *(const bf16x8*)(hA + ks * 32);
#pragma unroll
    for (int ks = 0; ks < 16; ++ks) {
      const int o = ks * 32 + quad * 8;
      accR = __builtin_amdgcn_mfma_f32_16x16x32_bf16(ha[ks], *(const bf16x8*)&wh[(     l16) * 520 + o], accR, 0, 0, 0);
      accZ = __builtin_amdgcn_mfma_f32_16x16x32_bf16(ha[ks], *(const bf16x8*)&wh[(16 + l16) * 520 + o], accZ, 0, 0, 0);
      accH = __builtin_amdgcn_mfma_f32_16x16x32_bf16(ha[ks], *(const bf16x8*)&wh[(32 + l16) * 520 + o], accH, 0, 0, 0);
    }

    // Gates in registers -> per-wave LDS transpose (no cross-wave traffic).
#pragma unroll
    for (int r = 0; r < 4; ++r) {
      float rs = accR[r], zs = accZ[r], hn = accH[r], nn = accN[r];
      if (!L) { rs += giR[r]; zs += giZ[r]; nn = giN[r]; }
      const float rg = __fdividef(1.0f, 1.0f + __expf(-rs));
      const float zg = __fdividef(1.0f, 1.0f + __expf(-zs));
      const float a2 = nn + rg * hn;
      const float e2 = __expf(2.0f * a2);
      const float cand = 1.0f - __fdividef(2.0f, e2 + 1.0f);   // tanh(a2)
      const float hnew = (1.0f - zg) * cand + zg * hprev[r];
      hprev[r] = hnew;
      hlds[b0 + r][l16] = (__bf16)hnew;
    }
    // DS ops are in-order per wave; fence only blocks compiler reordering.
    asm volatile("" ::: "memory");

    // Wave stores its own 16 rows: 64 x 8B coherent stores, drain, flag.
    __bf16* yout = Yown + (long)(t + 1) * 16384;
    {
      unsigned long long pv = *(const unsigned long long*)&hlds[srow][sch4];
      __bf16* dst = yout + (long)srow * 512 + c * 16 + sch4;
      asm volatile("global_store_dwordx2 %0, %1, off sc0 sc1"
                   :: "v"(dst), "v"(pv) : "memory");
    }
    asm volatile("s_waitcnt vmcnt(0)" ::: "memory");
    if (lane == 0)
      __hip_atomic_store(fOwn + (((c << 1) + w) << 5), (unsigned)(t + 1),
                         __ATOMIC_RELAXED, __HIP_MEMORY_SCOPE_AGENT);
  }

  // Persist f32 master for the next stage (kernel-boundary flush makes
  // plain stores safe).
#pragma unroll
  for (int r = 0; r < 4; ++r) hf[(b0 + r) * 512 + col] = hprev[r];
}

// ---------------------------------------------------------------------------
// Workspace layout (bytes), total ~59.7 MB:
//  GI    @ 0          12,582,912  (2048*1536 f32; reused enc0/dec0)
//  Xenc  @ 12,582,912  2,097,152
//  Xdec  @ 14,680,064  1,540,096
//  Y0e   @ 16,220,160  2,129,920  (65 slots: slot0 unused, 1..64 = y0 enc)
//  Y1e   @ 18,350,080  2,129,920  (slot 64 = enc layer1 final h)
//  Y0d   @ 20,480,000  1,572,864  (48 slots)
//  Y1d   @ 22,052,864  1,572,864  (slots 1..47 = D1 -> out GEMM A)
//  Wb0   @ 23,625,728  1,572,864  (enc_Wih0 bf16)
//  Wb2   @ 25,198,592  1,572,864  (dec_Wih0 bf16)
//  outWb @ 26,771,456 32,768,000
//  hf0   @ 59,539,456     65,536 ; hf1 @ 59,604,992 65,536
//  zb    @ 59,670,528     32,768  (bf16 zeros = initial h)
//  flags @ 59,703,296     32,768  (4 groups x 64 flags x 128B lines)
// ---------------------------------------------------------------------------
extern "C" void kernel_launch(void* const* d_in, const int* in_sizes, int n_in,
                              void* d_out, int out_size, void* d_ws, size_t ws_size,
                              hipStream_t stream)
{
  const int* src = (const int*)d_in[0];
  const int* trg = (const int*)d_in[1];
  const float* enc_emb  = (const float*)d_in[2];
  const float* enc_Wih0 = (const float*)d_in[3];
  const float* enc_Whh0 = (const float*)d_in[4];
  const float* enc_bih0 = (const float*)d_in[5];
  const float* enc_bhh0 = (const float*)d_in[6];
  const float* enc_Wih1 = (const float*)d_in[7];
  const float* enc_Whh1 = (const float*)d_in[8];
  const float* enc_bih1 = (const float*)d_in[9];
  const float* enc_bhh1 = (const float*)d_in[10];
  const float* dec_emb  = (const float*)d_in[11];
  const float* dec_Wih0 = (const float*)d_in[12];
  const float* dec_Whh0 = (const float*)d_in[13];
  const float* dec_bih0 = (const float*)d_in[14];
  const float* dec_bhh0 = (const float*)d_in[15];
  const float* dec_Wih1 = (const float*)d_in[16];
  const float* dec_Whh1 = (const float*)d_in[17];
  const float* dec_bih1 = (const float*)d_in[18];
  const float* dec_bhh1 = (const float*)d_in[19];
  const float* out_W    = (const float*)d_in[20];
  const float* out_b    = (const float*)d_in[21];

  char* ws = (char*)d_ws;
  float*  GI    = (float*)(ws + 0);
  __bf16* Xenc  = (__bf16*)(ws + 12582912);
  __bf16* Xdec  = (__bf16*)(ws + 14680064);
  __bf16* Y0e   = (__bf16*)(ws + 16220160);
  __bf16* Y1e   = (__bf16*)(ws + 18350080);
  __bf16* Y0d   = (__bf16*)(ws + 20480000);
  __bf16* Y1d   = (__bf16*)(ws + 22052864);
  __bf16* Wb0   = (__bf16*)(ws + 23625728);
  __bf16* Wb2   = (__bf16*)(ws + 25198592);
  __bf16* outWb = (__bf16*)(ws + 26771456);
  float*  hf0   = (float*)(ws + 59539456);
  float*  hf1   = (float*)(ws + 59604992);
  __bf16* zb    = (__bf16*)(ws + 59670528);
  unsigned* flags = (unsigned*)(ws + 59703296);   // 4 groups of 64x128B

  hipMemsetAsync(hf0, 0, 131072, stream);   // hf0 + hf1
  hipMemsetAsync(zb, 0, 32768, stream);
  hipMemsetAsync(flags, 0, 32768, stream);

  gather_cvt<<<2048, 64, 0, stream>>>(enc_emb, src, Xenc);
  gather_cvt<<<1504, 64, 0, stream>>>(dec_emb, trg, Xdec);   // rows 0..1503 = trg[:-1]
  cvt_f32_bf16<<<384, 256, 0, stream>>>(enc_Wih0, Wb0, 98304);
  cvt_f32_bf16<<<384, 256, 0, stream>>>(dec_Wih0, Wb2, 98304);
  cvt_f32_bf16<<<8000, 256, 0, stream>>>(out_W, outWb, 2048000);

  // encoder: GI for layer0, then both layers pipelined in one kernel
  gemm_tile<<<192, 256, 0, stream>>>(Xenc, Wb0, enc_bih0, GI, 2048, 1536, 12);
  gru2_pipe<<<64, 128, 0, stream>>>(GI, enc_Whh0, enc_bhh0,
                                    enc_Wih1, enc_bih1, enc_Whh1, enc_bhh1,
                                    Y0e, Y1e, zb, zb, hf0, hf1,
                                    flags + 0, flags + 2048, 64);
  // decoder: initial h = encoder finals (Y*e slot 64 bf16, hf* f32 in place)
  gemm_tile<<<144, 256, 0, stream>>>(Xdec, Wb2, dec_bih0, GI, 1504, 1536, 12);
  gru2_pipe<<<64, 128, 0, stream>>>(GI, dec_Whh0, dec_bhh0,
                                    dec_Wih1, dec_bih1, dec_Whh1, dec_bhh1,
                                    Y0d, Y1d, Y0e + 64 * 16384, Y1e + 64 * 16384, hf0, hf1,
                                    flags + 4096, flags + 6144, 47);

  // logits = D1 @ out_W^T + out_b  (D1 = Y1d slots 1..47, contiguous 1504x512)
  gemm_tile<<<3000, 256, 0, stream>>>(Y1d + 16384, outWb, out_b,
                                      (float*)d_out, 1504, 32000, 250);
}